// Round 9
// baseline (59.521 us; speedup 1.0000x reference)
//
#include <hip/hip_runtime.h>
#include <hip/hip_bf16.h>

// LinearAttention_41798621725051 on MI355X.
// Identity: (qk * v_h) / qk == v_h elementwise (qk strictly positive, finite),
// so reference == cumsum_b( v @ Wv^T ): one bf16 MFMA GEMM (M=16384, N=K=1024),
// batch-cumsum free in the epilogue (C/D frag rows = 4 batch entries of one s).
//
// R9: TLP round done right. BM=256/BN=128/BK=32, 8 waves (64x64 wave tile,
// acc=64), 48 KB LDS dbuf -> 2 blocks/CU (launch_bounds 512,4). A cvt-staged
// in-kernel (no big prepass); B pre-converted (2 MB) and gll-staged. R1/R8
// proven 0-conflict swizzles. One barrier/tile; co-resident block covers
// stalls, prologue and the epilogue write tail (m97 mechanism).

typedef short s16x8 __attribute__((ext_vector_type(8)));
typedef float f32x4 __attribute__((ext_vector_type(4)));

constexpr int M_ = 16384, N_ = 1024, K_ = 1024;
constexpr int BM = 256, BN = 128, BK = 32;
constexpr int KS = 32;                       // K / BK
constexpr size_t WS_NEED = 2097152;          // B bf16 = 2 MB

static __device__ __forceinline__ unsigned cvtpk(float lo, float hi) {
  unsigned r;
  asm("v_cvt_pk_bf16_f32 %0, %1, %2" : "=v"(r) : "v"(lo), "v"(hi));
  return r;
}

// ---------------- mini-prepass: Wv f32 -> bf16 (2 MB) ----------------
__global__ __launch_bounds__(256) void cvt_w(const float* __restrict__ w,
                                             unsigned short* __restrict__ wb) {
  const int t0 = blockIdx.x * 256 + threadIdx.x;   // grid 256 -> 65536 threads
#pragma unroll
  for (int r = 0; r < 4; ++r) {
    const int i = t0 + r * 65536;                  // 262144 float4 total
    float4 x = ((const float4*)w)[i];
    uint2 p; p.x = cvtpk(x.x, x.y); p.y = cvtpk(x.z, x.w);
    ((uint2*)wb)[i] = p;
  }
}

// ------------------------------ main GEMM ------------------------------
__global__ __launch_bounds__(512, 4) void la_gemm9(
    const float* __restrict__ Vp,            // (M,K) f32
    const unsigned short* __restrict__ Bb,   // (N,K) bf16 (from prepass)
    float* __restrict__ out) {
  __shared__ __align__(16) char lds[2][24576];   // per buf: A 16K | B 8K
  char* ldsb = (char*)lds;

  const int tid = threadIdx.x, lane = tid & 63, wave = tid >> 6;
  const int wr = wave >> 1, wc = wave & 1;       // 4x2 wave grid, 64x64 each
  const int l15 = lane & 15;

  // XCD-affine: the 8 nt-blocks of one mt share an XCD's L2 (A-strip reuse).
  const int gid = blockIdx.x;                    // 512 blocks, gid%8 = XCD
  const int xcd = gid & 7, t = gid >> 3;
  const int mt = xcd * 8 + (t >> 3);             // 0..63
  const int nt = t & 7;                          // 0..7

  // ---- A staging (reg cvt, R1-family swizzle chunk' = chunk ^ ((row>>1)&3))
  const int ar = tid >> 1, ah = tid & 1;         // 256 rows x 2 halves(16 f32)
  const float* sAp = Vp + (size_t)(mt * 256 + ar) * K_ + ah * 16;
  const int as = (ar >> 1) & 3;
  const int wbA0 = ar * 64 + (((2 * ah)     ^ as) << 4);
  const int wbA1 = ar * 64 + (((2 * ah + 1) ^ as) << 4);

  // ---- B staging via global_load_lds: linear LDS dest, pre-swizzled source.
  // dest row r = wave*16 + (lane>>2), dest chunk = lane&3  =>
  // src chunk = (lane&3) ^ ((r>>1)&3) = (lane&3) ^ ((lane>>3)&3).
  const int cg = ((lane & 3) ^ ((lane >> 3) & 3)) << 4;
  const char* srcB = (const char*)Bb +
      (size_t)(nt * 128 + wave * 16 + (lane >> 2)) * 2048 + cg;
  const int ldsB = 16384 + wave * 1024;          // + buf*24576

  // ---- fragment read bases (swizzle-matched)
  const int lswz = (((lane >> 4) ^ ((l15 >> 1) & 3)) << 4);
  const int rdA = (wr * 64 + l15) * 64 + lswz;           // + m*1024
  const int rdB = 16384 + (wc * 64 + l15) * 64 + lswz;   // + n*1024

  f32x4 acc[4][4] = {};
  float4 sa0, sa1, sa2, sa3;                     // A stage (16 f32)

#define LOADA(kt) do {                                                        \
    const float* p_ = sAp + (kt) * BK;                                        \
    sa0 = *(const float4*)p_;      sa1 = *(const float4*)(p_ + 4);            \
    sa2 = *(const float4*)(p_ + 8); sa3 = *(const float4*)(p_ + 12);          \
  } while (0)

#define GLLB(kt, buf)                                                         \
  __builtin_amdgcn_global_load_lds(                                           \
      (__attribute__((address_space(1))) void*)(void*)(srcB + (kt) * 64),     \
      (__attribute__((address_space(3))) void*)(void*)(ldsb + (buf) * 24576 + ldsB), \
      16, 0, 0)

#define WRITEA(buf) do {                                                      \
    char* A_ = ldsb + (buf) * 24576;                                          \
    uint4 w0_, w1_;                                                           \
    w0_.x = cvtpk(sa0.x, sa0.y); w0_.y = cvtpk(sa0.z, sa0.w);                 \
    w0_.z = cvtpk(sa1.x, sa1.y); w0_.w = cvtpk(sa1.z, sa1.w);                 \
    w1_.x = cvtpk(sa2.x, sa2.y); w1_.y = cvtpk(sa2.z, sa2.w);                 \
    w1_.z = cvtpk(sa3.x, sa3.y); w1_.w = cvtpk(sa3.z, sa3.w);                 \
    *(uint4*)(A_ + wbA0) = w0_;                                               \
    *(uint4*)(A_ + wbA1) = w1_;                                               \
  } while (0)

#define COMPUTE(buf) do {                                                     \
    const char* U_ = ldsb + (buf) * 24576;                                    \
    s16x8 af[4], bf[4];                                                       \
    _Pragma("unroll") for (int n_ = 0; n_ < 4; ++n_)                          \
      bf[n_] = *(const s16x8*)(U_ + rdB + n_ * 1024);                         \
    _Pragma("unroll") for (int m_ = 0; m_ < 4; ++m_)                          \
      af[m_] = *(const s16x8*)(U_ + rdA + m_ * 1024);                         \
    __builtin_amdgcn_s_setprio(1);                                            \
    _Pragma("unroll") for (int m_ = 0; m_ < 4; ++m_)                          \
    _Pragma("unroll") for (int n_ = 0; n_ < 4; ++n_)                          \
        acc[m_][n_] = __builtin_amdgcn_mfma_f32_16x16x32_bf16(                \
            af[m_], bf[n_], acc[m_][n_], 0, 0, 0);                            \
    __builtin_amdgcn_s_setprio(0);                                            \
  } while (0)

  // ---- prologue: tile 0 into buf 0
  GLLB(0, 0);
  LOADA(0);
  WRITEA(0);
  __syncthreads();

  // ---- main loop: 1 barrier/tile; next tile's loads in flight across
  // compute; co-resident block covers the drain.
  for (int kt = 0; kt < KS; ++kt) {
    const int cur = kt & 1;
    const bool pf = (kt + 1 < KS);
    if (pf) { GLLB(kt + 1, cur ^ 1); LOADA(kt + 1); }
    COMPUTE(cur);
    if (pf) WRITEA(cur ^ 1);
    __syncthreads();
  }

  // ---- epilogue: batch-cumsum = prefix over f32x4 (rows s*4 + 0..3)
#pragma unroll
  for (int m = 0; m < 4; ++m) {
    const int row0 = mt * 256 + wr * 64 + m * 16 + ((lane >> 4) << 2);
#pragma unroll
    for (int n = 0; n < 4; ++n) {
      f32x4 a = acc[m][n];
      a.y += a.x;  a.z += a.y;  a.w += a.z;
      const int col = nt * 128 + wc * 64 + n * 16 + l15;
      out[(size_t)(row0 + 0) * N_ + col] = a.x;
      out[(size_t)(row0 + 1) * N_ + col] = a.y;
      out[(size_t)(row0 + 2) * N_ + col] = a.z;
      out[(size_t)(row0 + 3) * N_ + col] = a.w;
    }
  }
#undef LOADA
#undef GLLB
#undef WRITEA
#undef COMPUTE
}

// ------------- fallback: R3 fused kernel (proven, 50 µs) -------------
__global__ __launch_bounds__(512, 2) void la_gemm_fb(
    const float* __restrict__ Vp, const float* __restrict__ Wp, float* __restrict__ out) {
  extern __shared__ char lds[];
  const int tid = threadIdx.x, lane = tid & 63, wave = tid >> 6;
  const int wr = wave >> 2, wc = wave & 3;
  const int gid = blockIdx.x, xcd = gid & 7, q = gid >> 3;
  const int mt = xcd * 8 + (q >> 2), nt = q & 3;
  const int srow = tid >> 3, schunk = tid & 7;
  const float* sAp = Vp + (size_t)(mt * 256 + srow) * K_ + schunk * 8;
  const float* sBp = Wp + (size_t)(nt * 256 + srow) * K_ + schunk * 8;
  const int wbyte = srow * 128 + ((schunk ^ (srow & 7)) << 4);
  const int basa0 = (wr * 128 + (lane & 15)) * 128 + (((lane >> 4) ^ (lane & 7)) << 4);
  const int basb0 = (wc * 64 + (lane & 15)) * 128 + (((lane >> 4) ^ (lane & 7)) << 4);
  f32x4 acc[8][4] = {};
  float4 sa[8], sb[8];
  auto loadset = [&](int kt) {
#pragma unroll
    for (int i = 0; i < 4; ++i) {
      const float* pa = sAp + kt * 64 + i * (64 * K_);
      const float* pb = sBp + kt * 64 + i * (64 * K_);
      sa[2*i] = *(const float4*)pa; sa[2*i+1] = *(const float4*)(pa + 4);
      sb[2*i] = *(const float4*)pb; sb[2*i+1] = *(const float4*)(pb + 4);
    }
  };
  auto cvtwrite = [&](int buf) {
    char* A = lds + buf * 65536; char* B = A + 32768;
#pragma unroll
    for (int i = 0; i < 4; ++i) {
      uint4 wa, wb;
      wa.x = cvtpk(sa[2*i].x, sa[2*i].y);     wa.y = cvtpk(sa[2*i].z, sa[2*i].w);
      wa.z = cvtpk(sa[2*i+1].x, sa[2*i+1].y); wa.w = cvtpk(sa[2*i+1].z, sa[2*i+1].w);
      wb.x = cvtpk(sb[2*i].x, sb[2*i].y);     wb.y = cvtpk(sb[2*i].z, sb[2*i].w);
      wb.z = cvtpk(sb[2*i+1].x, sb[2*i+1].y); wb.w = cvtpk(sb[2*i+1].z, sb[2*i+1].w);
      *(uint4*)(A + wbyte + i * 8192) = wa;
      *(uint4*)(B + wbyte + i * 8192) = wb;
    }
  };
  auto compute = [&](int buf) {
    const char* A = lds + buf * 65536; const char* B = A + 32768;
#pragma unroll
    for (int kk = 0; kk < 2; ++kk) {
      const int ba = basa0 ^ (kk ? 64 : 0), bb = basb0 ^ (kk ? 64 : 0);
      s16x8 bf[4];
#pragma unroll
      for (int n = 0; n < 4; ++n) bf[n] = *(const s16x8*)(B + bb + n * 2048);
#pragma unroll
      for (int mh = 0; mh < 2; ++mh) {
        s16x8 af[4];
#pragma unroll
        for (int m = 0; m < 4; ++m) af[m] = *(const s16x8*)(A + ba + (mh * 4 + m) * 2048);
        __builtin_amdgcn_s_setprio(1);
#pragma unroll
        for (int m = 0; m < 4; ++m)
#pragma unroll
          for (int n = 0; n < 4; ++n)
            acc[mh*4+m][n] = __builtin_amdgcn_mfma_f32_16x16x32_bf16(af[m], bf[n], acc[mh*4+m][n], 0, 0, 0);
        __builtin_amdgcn_s_setprio(0);
      }
    }
  };
  loadset(0); cvtwrite(0); __syncthreads();
  for (int kt = 0; kt < 16; ++kt) {
    const int cur = kt & 1;
    if (kt + 1 < 16) loadset(kt + 1);
    compute(cur);
    if (kt + 1 < 16) cvtwrite(cur ^ 1);
    __syncthreads();
  }
#pragma unroll
  for (int m = 0; m < 8; ++m) {
    const int row0 = mt * 256 + wr * 128 + m * 16 + ((lane >> 4) << 2);
#pragma unroll
    for (int n = 0; n < 4; ++n) {
      f32x4 a = acc[m][n];
      a.y += a.x; a.z += a.y; a.w += a.z;
      const int col = nt * 256 + wc * 64 + n * 16 + (lane & 15);
      out[(size_t)(row0 + 0) * N_ + col] = a.x;
      out[(size_t)(row0 + 1) * N_ + col] = a.y;
      out[(size_t)(row0 + 2) * N_ + col] = a.z;
      out[(size_t)(row0 + 3) * N_ + col] = a.w;
    }
  }
}

extern "C" void kernel_launch(void* const* d_in, const int* in_sizes, int n_in,
                              void* d_out, int out_size, void* d_ws, size_t ws_size,
                              hipStream_t stream) {
  // setup_inputs order: q, k, v, Wq, Wk, Wv — only v and Wv matter.
  const float* v  = (const float*)d_in[2];
  const float* Wv = (const float*)d_in[5];
  float* out = (float*)d_out;
  (void)in_sizes; (void)n_in; (void)out_size;

  if (ws_size >= WS_NEED) {
    unsigned short* wb = (unsigned short*)d_ws;
    cvt_w<<<dim3(256), dim3(256), 0, stream>>>(Wv, wb);
    la_gemm9<<<dim3(512), dim3(512), 0, stream>>>(v, wb, out);
  } else {
    hipFuncSetAttribute((const void*)la_gemm_fb,
                        hipFuncAttributeMaxDynamicSharedMemorySize, 131072);
    la_gemm_fb<<<dim3(256), dim3(512), 131072, stream>>>(v, Wv, out);
  }
}

// Round 10
// 58.752 us; speedup vs baseline: 1.0131x; 1.0131x over previous
//
#include <hip/hip_runtime.h>
#include <hip/hip_bf16.h>

// LinearAttention_41798621725051 on MI355X.
// Identity: (qk * v_h) / qk == v_h elementwise (qk strictly positive, finite),
// so reference == cumsum_b( v @ Wv^T ): one bf16 MFMA GEMM (M=16384, N=K=1024),
// batch-cumsum free in the epilogue (C/D frag rows = 4 batch entries of one s).
//
// R10: 4 independent barrier domains per CU. 128x128 tile, BK=32, 4 waves
// (2x2 of 64x64), ring-2 LDS = 32 KB/block -> 4 blocks/CU, grid 1024 fully
// resident (16 waves/CU). Fused A reg-stage (f32->bf16, no 64MB prepass);
// B via 2MB bf16 mini-prepass + global_load_lds. R1-proven BK=32 swizzle
// (0 conflicts). Plain 2-phase loop; co-resident blocks cover the stalls
// and de-synchronize the write tail (m97 mechanism at 4x domains).

typedef short s16x8 __attribute__((ext_vector_type(8)));
typedef float f32x4 __attribute__((ext_vector_type(4)));

constexpr int M_ = 16384, N_ = 1024, K_ = 1024;
constexpr int KS = 32;                       // K / BK, BK = 32
constexpr size_t WS_NEED = 2097152;          // B bf16 = 2 MB

static __device__ __forceinline__ unsigned cvtpk(float lo, float hi) {
  unsigned r;
  asm("v_cvt_pk_bf16_f32 %0, %1, %2" : "=v"(r) : "v"(lo), "v"(hi));
  return r;
}

// ---------------- mini-prepass: Wv f32 -> bf16 (2 MB) ----------------
__global__ __launch_bounds__(256) void cvt_w(const float* __restrict__ w,
                                             unsigned short* __restrict__ wb) {
  const int t0 = blockIdx.x * 256 + threadIdx.x;   // grid 256 -> 65536 threads
#pragma unroll
  for (int r = 0; r < 4; ++r) {
    const int i = t0 + r * 65536;                  // 262144 float4 total
    float4 x = ((const float4*)w)[i];
    uint2 p; p.x = cvtpk(x.x, x.y); p.y = cvtpk(x.z, x.w);
    ((uint2*)wb)[i] = p;
  }
}

// ------------------------------ main GEMM ------------------------------
__global__ __launch_bounds__(256, 4) void la_gemm10(
    const float* __restrict__ Vp,            // (M,K) f32
    const unsigned short* __restrict__ Bb,   // (N,K) bf16
    float* __restrict__ out) {
  // ring-2: per buf A 8 KB | B 8 KB  (tile 128 x 32 bf16 each)
  __shared__ __align__(16) char lds[2][16384];
  char* ldsb = (char*)lds;

  const int tid = threadIdx.x, lane = tid & 63, wave = tid >> 6;  // 4 waves
  const int wr = wave >> 1, wc = wave & 1;   // 2x2 wave grid, 64x64 each
  const int l15 = lane & 15;

  // XCD-affine: 8 nt-blocks of one mt land on one XCD; concurrent 8-block
  // groups share the A strip in L2 (v also fully L3-resident at 64 MB).
  const int gid = blockIdx.x;                // 1024 blocks, gid%8 = XCD
  const int xcd = gid & 7, t = gid >> 3;     // t 0..127
  const int mt = xcd * 16 + (t >> 3);        // 0..127
  const int nt = t & 7;                      // 0..7

  // ---- A staging (reg cvt). Slots: 128 rows x 4 chunks(16B); thread ->
  // rows {sr, 64+sr}, chunk sc. Swizzle chunk' = sc ^ ((row>>1)&3) (R1).
  const int sr = tid >> 2;                   // 0..63
  const int sc = tid & 3;
  const float* sAp = Vp + (size_t)(mt * 128 + sr) * K_ + sc * 8;  // +i*64*K +kt*32
  const int wbA = sr * 64 + ((sc ^ ((sr >> 1) & 3)) << 4);        // +i*4096

  // ---- B staging via global_load_lds: linear LDS dest (1KB = 16 rows x 64B),
  // pre-swizzled source: lane -> row r0+(lane>>2), chunk lane&3;
  // src chunk' = (lane&3) ^ ((row>>1)&3) = (lane&3) ^ ((lane>>3)&3).
  const int cg = ((lane & 3) ^ ((lane >> 3) & 3)) << 4;
  const char* srcB = (const char*)Bb +
      (size_t)(nt * 128 + wave * 32 + (lane >> 2)) * 2048 + cg;   // +u*16*2048 +kt*64
  const int ldsBw = 8192 + wave * 2048;      // +u*1024 (+buf*16384)

  // ---- fragment read bases (swizzle-matched; chunk = lane>>4)
  const int lsw = (((lane >> 4) ^ ((l15 >> 1) & 3)) << 4);
  const int rdA = (wr * 64 + l15) * 64 + lsw;          // + m*1024
  const int rdB = 8192 + (wc * 64 + l15) * 64 + lsw;   // + n*1024

  f32x4 acc[4][4] = {};
  float4 sa0, sa1, sa2, sa3;                 // A stage: 2 rows x 8 f32

#define LOADA(kt) do {                                                        \
    const float* p0_ = sAp + (kt) * 32;                                       \
    const float* p1_ = p0_ + 64 * K_;                                         \
    sa0 = *(const float4*)p0_;  sa1 = *(const float4*)(p0_ + 4);              \
    sa2 = *(const float4*)p1_;  sa3 = *(const float4*)(p1_ + 4);              \
  } while (0)

#define WRITEA(buf) do {                                                      \
    char* A_ = ldsb + (buf) * 16384;                                          \
    uint4 w0_, w1_;                                                           \
    w0_.x = cvtpk(sa0.x, sa0.y); w0_.y = cvtpk(sa0.z, sa0.w);                 \
    w0_.z = cvtpk(sa1.x, sa1.y); w0_.w = cvtpk(sa1.z, sa1.w);                 \
    w1_.x = cvtpk(sa2.x, sa2.y); w1_.y = cvtpk(sa2.z, sa2.w);                 \
    w1_.z = cvtpk(sa3.x, sa3.y); w1_.w = cvtpk(sa3.z, sa3.w);                 \
    *(uint4*)(A_ + wbA) = w0_;                                                \
    *(uint4*)(A_ + wbA + 4096) = w1_;                                         \
  } while (0)

#define GLLB(kt, buf) do {                                                    \
    __builtin_amdgcn_global_load_lds(                                         \
        (__attribute__((address_space(1))) void*)(void*)(srcB + (kt) * 64),   \
        (__attribute__((address_space(3))) void*)(void*)(ldsb + (buf) * 16384 + ldsBw), \
        16, 0, 0);                                                            \
    __builtin_amdgcn_global_load_lds(                                         \
        (__attribute__((address_space(1))) void*)(void*)(srcB + 32768 + (kt) * 64), \
        (__attribute__((address_space(3))) void*)(void*)(ldsb + (buf) * 16384 + ldsBw + 1024), \
        16, 0, 0);                                                            \
  } while (0)

#define COMPUTE(buf) do {                                                     \
    const char* U_ = ldsb + (buf) * 16384;                                    \
    s16x8 af[4], bf[4];                                                       \
    _Pragma("unroll") for (int n_ = 0; n_ < 4; ++n_)                          \
      bf[n_] = *(const s16x8*)(U_ + rdB + n_ * 1024);                         \
    _Pragma("unroll") for (int m_ = 0; m_ < 4; ++m_)                          \
      af[m_] = *(const s16x8*)(U_ + rdA + m_ * 1024);                         \
    __builtin_amdgcn_s_setprio(1);                                            \
    _Pragma("unroll") for (int m_ = 0; m_ < 4; ++m_)                          \
    _Pragma("unroll") for (int n_ = 0; n_ < 4; ++n_)                          \
        acc[m_][n_] = __builtin_amdgcn_mfma_f32_16x16x32_bf16(                \
            af[m_], bf[n_], acc[m_][n_], 0, 0, 0);                            \
    __builtin_amdgcn_s_setprio(0);                                            \
  } while (0)

  // ---- prologue: tile 0 into buf 0
  GLLB(0, 0);
  LOADA(0);
  WRITEA(0);            // compiler inserts the vmcnt for the loads
  __syncthreads();      // drains gll (vmcnt) + ds_writes (lgkm)

  // ---- main loop: one barrier per tile; next tile's loads in flight
  // across compute; co-resident blocks cover every stall window.
  for (int kt = 0; kt < KS; ++kt) {
    const int cur = kt & 1;
    const bool pf = (kt + 1 < KS);
    if (pf) { GLLB(kt + 1, cur ^ 1); LOADA(kt + 1); }
    COMPUTE(cur);
    if (pf) WRITEA(cur ^ 1);
    __syncthreads();
  }

  // ---- epilogue: batch-cumsum = prefix over f32x4 (rows s*4 + 0..3)
#pragma unroll
  for (int m = 0; m < 4; ++m) {
    const int row0 = mt * 128 + wr * 64 + m * 16 + ((lane >> 4) << 2);
#pragma unroll
    for (int n = 0; n < 4; ++n) {
      f32x4 a = acc[m][n];
      a.y += a.x;  a.z += a.y;  a.w += a.z;
      const int col = nt * 128 + wc * 64 + n * 16 + l15;
      out[(size_t)(row0 + 0) * N_ + col] = a.x;
      out[(size_t)(row0 + 1) * N_ + col] = a.y;
      out[(size_t)(row0 + 2) * N_ + col] = a.z;
      out[(size_t)(row0 + 3) * N_ + col] = a.w;
    }
  }
#undef LOADA
#undef WRITEA
#undef GLLB
#undef COMPUTE
}

// ------------- fallback: R3 fused kernel (proven, 50 µs) -------------
__global__ __launch_bounds__(512, 2) void la_gemm_fb(
    const float* __restrict__ Vp, const float* __restrict__ Wp, float* __restrict__ out) {
  extern __shared__ char lds[];
  const int tid = threadIdx.x, lane = tid & 63, wave = tid >> 6;
  const int wr = wave >> 2, wc = wave & 3;
  const int gid = blockIdx.x, xcd = gid & 7, q = gid >> 3;
  const int mt = xcd * 8 + (q >> 2), nt = q & 3;
  const int srow = tid >> 3, schunk = tid & 7;
  const float* sAp = Vp + (size_t)(mt * 256 + srow) * K_ + schunk * 8;
  const float* sBp = Wp + (size_t)(nt * 256 + srow) * K_ + schunk * 8;
  const int wbyte = srow * 128 + ((schunk ^ (srow & 7)) << 4);
  const int basa0 = (wr * 128 + (lane & 15)) * 128 + (((lane >> 4) ^ (lane & 7)) << 4);
  const int basb0 = (wc * 64 + (lane & 15)) * 128 + (((lane >> 4) ^ (lane & 7)) << 4);
  f32x4 acc[8][4] = {};
  float4 sa[8], sb[8];
  auto loadset = [&](int kt) {
#pragma unroll
    for (int i = 0; i < 4; ++i) {
      const float* pa = sAp + kt * 64 + i * (64 * K_);
      const float* pb = sBp + kt * 64 + i * (64 * K_);
      sa[2*i] = *(const float4*)pa; sa[2*i+1] = *(const float4*)(pa + 4);
      sb[2*i] = *(const float4*)pb; sb[2*i+1] = *(const float4*)(pb + 4);
    }
  };
  auto cvtwrite = [&](int buf) {
    char* A = lds + buf * 65536; char* B = A + 32768;
#pragma unroll
    for (int i = 0; i < 4; ++i) {
      uint4 wa, wb;
      wa.x = cvtpk(sa[2*i].x, sa[2*i].y);     wa.y = cvtpk(sa[2*i].z, sa[2*i].w);
      wa.z = cvtpk(sa[2*i+1].x, sa[2*i+1].y); wa.w = cvtpk(sa[2*i+1].z, sa[2*i+1].w);
      wb.x = cvtpk(sb[2*i].x, sb[2*i].y);     wb.y = cvtpk(sb[2*i].z, sb[2*i].w);
      wb.z = cvtpk(sb[2*i+1].x, sb[2*i+1].y); wb.w = cvtpk(sb[2*i+1].z, sb[2*i+1].w);
      *(uint4*)(A + wbyte + i * 8192) = wa;
      *(uint4*)(B + wbyte + i * 8192) = wb;
    }
  };
  auto compute = [&](int buf) {
    const char* A = lds + buf * 65536; const char* B = A + 32768;
#pragma unroll
    for (int kk = 0; kk < 2; ++kk) {
      const int ba = basa0 ^ (kk ? 64 : 0), bb = basb0 ^ (kk ? 64 : 0);
      s16x8 bf[4];
#pragma unroll
      for (int n = 0; n < 4; ++n) bf[n] = *(const s16x8*)(B + bb + n * 2048);
#pragma unroll
      for (int mh = 0; mh < 2; ++mh) {
        s16x8 af[4];
#pragma unroll
        for (int m = 0; m < 4; ++m) af[m] = *(const s16x8*)(A + ba + (mh * 4 + m) * 2048);
        __builtin_amdgcn_s_setprio(1);
#pragma unroll
        for (int m = 0; m < 4; ++m)
#pragma unroll
          for (int n = 0; n < 4; ++n)
            acc[mh*4+m][n] = __builtin_amdgcn_mfma_f32_16x16x32_bf16(af[m], bf[n], acc[mh*4+m][n], 0, 0, 0);
        __builtin_amdgcn_s_setprio(0);
      }
    }
  };
  loadset(0); cvtwrite(0); __syncthreads();
  for (int kt = 0; kt < 16; ++kt) {
    const int cur = kt & 1;
    if (kt + 1 < 16) loadset(kt + 1);
    compute(cur);
    if (kt + 1 < 16) cvtwrite(cur ^ 1);
    __syncthreads();
  }
#pragma unroll
  for (int m = 0; m < 8; ++m) {
    const int row0 = mt * 256 + wr * 128 + m * 16 + ((lane >> 4) << 2);
#pragma unroll
    for (int n = 0; n < 4; ++n) {
      f32x4 a = acc[m][n];
      a.y += a.x; a.z += a.y; a.w += a.z;
      const int col = nt * 256 + wc * 64 + n * 16 + (lane & 15);
      out[(size_t)(row0 + 0) * N_ + col] = a.x;
      out[(size_t)(row0 + 1) * N_ + col] = a.y;
      out[(size_t)(row0 + 2) * N_ + col] = a.z;
      out[(size_t)(row0 + 3) * N_ + col] = a.w;
    }
  }
}

extern "C" void kernel_launch(void* const* d_in, const int* in_sizes, int n_in,
                              void* d_out, int out_size, void* d_ws, size_t ws_size,
                              hipStream_t stream) {
  // setup_inputs order: q, k, v, Wq, Wk, Wv — only v and Wv matter.
  const float* v  = (const float*)d_in[2];
  const float* Wv = (const float*)d_in[5];
  float* out = (float*)d_out;
  (void)in_sizes; (void)n_in; (void)out_size;

  if (ws_size >= WS_NEED) {
    unsigned short* wb = (unsigned short*)d_ws;
    cvt_w<<<dim3(256), dim3(256), 0, stream>>>(Wv, wb);
    la_gemm10<<<dim3(1024), dim3(256), 0, stream>>>(v, wb, out);
  } else {
    hipFuncSetAttribute((const void*)la_gemm_fb,
                        hipFuncAttributeMaxDynamicSharedMemorySize, 131072);
    la_gemm_fb<<<dim3(256), dim3(512), 131072, stream>>>(v, Wv, out);
  }
}

// Round 11
// 51.867 us; speedup vs baseline: 1.1476x; 1.1328x over previous
//
#include <hip/hip_runtime.h>
#include <hip/hip_bf16.h>

// LinearAttention_41798621725051 on MI355X.
// Identity: (qk * v_h) / qk == v_h elementwise (qk strictly positive, finite),
// so reference == cumsum_b( v @ Wv^T ): one bf16 MFMA GEMM (M=16384, N=K=1024),
// batch-cumsum free in the epilogue (C/D frag rows = 4 batch entries of one s).
//
// R11: surgical delta on R3 (best, 50.25 us). Keep the fused 2-phase 256x256
// BK=64 structure; replace ONLY the B staging path: Wv pre-converted to bf16
// (2 MB, ~1.5 us) and staged via global_load_lds with R6's refchecked
// pre-swizzled-source involution. Removes B's f32 L2 reads, B's cvt VALU and
// half the ds_writes. A stays fused (f32->bf16 in-kernel; no 64 MB prepass).
// A's cvt+ds_write placed between the two kk-halves of compute for overlap.

typedef short s16x8 __attribute__((ext_vector_type(8)));
typedef float f32x4 __attribute__((ext_vector_type(4)));

constexpr int M_ = 16384, N_ = 1024, K_ = 1024;
constexpr int KT = 16;                       // K / 64
constexpr size_t WS_NEED = 2097152;          // Wv bf16 = 2 MB

static __device__ __forceinline__ unsigned cvtpk(float lo, float hi) {
  unsigned r;
  asm("v_cvt_pk_bf16_f32 %0, %1, %2" : "=v"(r) : "v"(lo), "v"(hi));
  return r;
}

// ---------------- mini-prepass: Wv f32 -> bf16 (2 MB) ----------------
__global__ __launch_bounds__(256) void cvt_w(const float* __restrict__ w,
                                             unsigned short* __restrict__ wb) {
  const int t0 = blockIdx.x * 256 + threadIdx.x;   // grid 256 -> 65536 threads
#pragma unroll
  for (int r = 0; r < 4; ++r) {
    const int i = t0 + r * 65536;                  // 262144 float4 total
    float4 x = ((const float4*)w)[i];
    uint2 p; p.x = cvtpk(x.x, x.y); p.y = cvtpk(x.z, x.w);
    ((uint2*)wb)[i] = p;
  }
}

// ------------------------------ main GEMM ------------------------------
#define GLL(srcp, ldsoff)                                                     \
  __builtin_amdgcn_global_load_lds(                                           \
      (__attribute__((address_space(1))) void*)(void*)(srcp),                 \
      (__attribute__((address_space(3))) void*)(void*)(lds + (ldsoff)),       \
      16, 0, 0)

__global__ __launch_bounds__(512, 2) void la_gemm11(
    const float* __restrict__ Vp,            // (M,K) f32
    const unsigned short* __restrict__ Bb,   // (N,K) bf16 (prepass)
    float* __restrict__ out) {
  extern __shared__ char lds[];   // [A0 32K][A1 32K][B0 32K][B1 32K]

  const int tid = threadIdx.x, lane = tid & 63, wave = tid >> 6;
  const int wr = wave >> 2, wc = wave & 3;   // 2x4 wave grid, 128x64 each
  const int l15 = lane & 15, l7 = lane & 7, l3 = lane >> 3;

  // XCD-affine: 4 nt-blocks of one mt share an XCD's L2 (A-strip reuse).
  const int gid = blockIdx.x;
  const int xcd = gid & 7, q = gid >> 3;
  const int mt = xcd * 8 + (q >> 2), nt = q & 3;

  // ---- A staging (R3-proven): rows srow + i*64, chunk schunk (8 f32).
  // Swizzle: chunk' = chunk ^ (row & 7).
  const int srow = tid >> 3, schunk = tid & 7;
  const float* sAp = Vp + (size_t)(mt * 256 + srow) * K_ + schunk * 8;
  const int wbyte = srow * 128 + ((schunk ^ (srow & 7)) << 4);

  // ---- B staging via global_load_lds (R6-proven): linear LDS dest
  // (wave*1024 + lane*16), source row = nt*256 + h*128 + j*64 + wave*8 + l3,
  // source chunk = dest chunk ^ (row&7) = l7 ^ l3.
  const int sch = ((l7 ^ l3) & 7) << 4;
  const char* sB[2][2];
#pragma unroll
  for (int h = 0; h < 2; ++h)
#pragma unroll
    for (int j = 0; j < 2; ++j)
      sB[h][j] = (const char*)Bb +
          (size_t)(nt * 256 + h * 128 + j * 64 + wave * 8 + l3) * 2048 + sch;
  const int ldsBw = wave * 1024;             // + 65536 + buf*32768 + h/j offs

  // ---- fragment read bases (swizzle-matched; kk=1 => ^64)
  const int basa = wr * 16384 + l15 * 128 + (((lane >> 4) ^ l7) << 4);
  const int basb = (wc * 64 + l15) * 128 + (((lane >> 4) ^ l7) << 4);

  f32x4 acc[8][4] = {};
  float4 sa[8];

#define LOADA(kt) do {                                                        \
    _Pragma("unroll")                                                         \
    for (int i_ = 0; i_ < 4; ++i_) {                                          \
      const float* p_ = sAp + (kt) * 64 + i_ * (64 * K_);                     \
      sa[2*i_]   = *(const float4*)p_;                                        \
      sa[2*i_+1] = *(const float4*)(p_ + 4);                                  \
    }                                                                         \
  } while (0)

#define WRITEA(buf) do {                                                      \
    char* A_ = lds + (buf) * 32768;                                           \
    _Pragma("unroll")                                                         \
    for (int i_ = 0; i_ < 4; ++i_) {                                          \
      uint4 w_;                                                               \
      w_.x = cvtpk(sa[2*i_].x,   sa[2*i_].y);                                 \
      w_.y = cvtpk(sa[2*i_].z,   sa[2*i_].w);                                 \
      w_.z = cvtpk(sa[2*i_+1].x, sa[2*i_+1].y);                               \
      w_.w = cvtpk(sa[2*i_+1].z, sa[2*i_+1].w);                               \
      *(uint4*)(A_ + wbyte + i_ * 8192) = w_;                                 \
    }                                                                         \
  } while (0)

#define GLLB(kt, buf) do {                                                    \
    const int bb_ = 65536 + (buf) * 32768;                                    \
    GLL(sB[0][0] + (kt) * 128, bb_ + 0     + ldsBw);                          \
    GLL(sB[0][1] + (kt) * 128, bb_ + 8192  + ldsBw);                          \
    GLL(sB[1][0] + (kt) * 128, bb_ + 16384 + ldsBw);                          \
    GLL(sB[1][1] + (kt) * 128, bb_ + 24576 + ldsBw);                          \
  } while (0)

#define COMPUTE_KK(buf, kk) do {                                              \
    const char* A_ = lds + (buf) * 32768;                                     \
    const char* B_ = lds + 65536 + (buf) * 32768;                             \
    const int xo_ = (kk) ? 64 : 0;                                            \
    s16x8 bf[4];                                                              \
    _Pragma("unroll")                                                         \
    for (int n_ = 0; n_ < 4; ++n_)                                            \
      bf[n_] = *(const s16x8*)(B_ + ((basb + n_ * 2048) ^ xo_));              \
    _Pragma("unroll")                                                         \
    for (int mh_ = 0; mh_ < 2; ++mh_) {                                       \
      s16x8 af[4];                                                            \
      _Pragma("unroll")                                                       \
      for (int m_ = 0; m_ < 4; ++m_)                                          \
        af[m_] = *(const s16x8*)(A_ + ((basa + (mh_*4 + m_) * 2048) ^ xo_));  \
      __builtin_amdgcn_s_setprio(1);                                          \
      _Pragma("unroll")                                                       \
      for (int m_ = 0; m_ < 4; ++m_)                                          \
        _Pragma("unroll")                                                     \
        for (int n_ = 0; n_ < 4; ++n_)                                        \
          acc[mh_*4 + m_][n_] = __builtin_amdgcn_mfma_f32_16x16x32_bf16(      \
              af[m_], bf[n_], acc[mh_*4 + m_][n_], 0, 0, 0);                  \
      __builtin_amdgcn_s_setprio(0);                                         \
    }                                                                         \
  } while (0)

  // ---- prologue: tile 0 into buf 0
  GLLB(0, 0);
  LOADA(0);
  WRITEA(0);
  __syncthreads();    // drains gll (vmcnt) + ds_writes (lgkm) for all waves

  // ---- main loop: R3's 2-phase structure; B staged by gll, A's cvt+write
  // sandwiched between the kk halves (overlaps kk0's MFMA, no new barriers).
  for (int kt = 0; kt < KT; ++kt) {
    const int cur = kt & 1;
    const bool pf = (kt + 1 < KT);
    if (pf) { GLLB(kt + 1, cur ^ 1); LOADA(kt + 1); }
    COMPUTE_KK(cur, 0);
    if (pf) WRITEA(cur ^ 1);
    COMPUTE_KK(cur, 1);
    __syncthreads();
  }

  // ---- epilogue: batch-cumsum = prefix over f32x4 (rows s*4 + 0..3)
#pragma unroll
  for (int m = 0; m < 8; ++m) {
    const int row0 = mt * 256 + wr * 128 + m * 16 + ((lane >> 4) << 2);
#pragma unroll
    for (int n = 0; n < 4; ++n) {
      f32x4 a = acc[m][n];
      a.y += a.x;  a.z += a.y;  a.w += a.z;
      const int col = nt * 256 + wc * 64 + n * 16 + l15;
      out[(size_t)(row0 + 0) * N_ + col] = a.x;
      out[(size_t)(row0 + 1) * N_ + col] = a.y;
      out[(size_t)(row0 + 2) * N_ + col] = a.z;
      out[(size_t)(row0 + 3) * N_ + col] = a.w;
    }
  }
#undef LOADA
#undef WRITEA
#undef GLLB
#undef COMPUTE_KK
}

// ------------- fallback: R3 fused kernel (proven, 50 µs) -------------
__global__ __launch_bounds__(512, 2) void la_gemm_fb(
    const float* __restrict__ Vp, const float* __restrict__ Wp, float* __restrict__ out) {
  extern __shared__ char lds[];
  const int tid = threadIdx.x, lane = tid & 63, wave = tid >> 6;
  const int wr = wave >> 2, wc = wave & 3;
  const int gid = blockIdx.x, xcd = gid & 7, q = gid >> 3;
  const int mt = xcd * 8 + (q >> 2), nt = q & 3;
  const int srow = tid >> 3, schunk = tid & 7;
  const float* sAp = Vp + (size_t)(mt * 256 + srow) * K_ + schunk * 8;
  const float* sBp = Wp + (size_t)(nt * 256 + srow) * K_ + schunk * 8;
  const int wbyte = srow * 128 + ((schunk ^ (srow & 7)) << 4);
  const int basa0 = (wr * 128 + (lane & 15)) * 128 + (((lane >> 4) ^ (lane & 7)) << 4);
  const int basb0 = (wc * 64 + (lane & 15)) * 128 + (((lane >> 4) ^ (lane & 7)) << 4);
  f32x4 acc[8][4] = {};
  float4 sa[8], sb[8];
  auto cvtpk_ = [](float lo, float hi) {
    unsigned r; asm("v_cvt_pk_bf16_f32 %0, %1, %2" : "=v"(r) : "v"(lo), "v"(hi)); return r;
  };
  auto loadset = [&](int kt) {
#pragma unroll
    for (int i = 0; i < 4; ++i) {
      const float* pa = sAp + kt * 64 + i * (64 * K_);
      const float* pb = sBp + kt * 64 + i * (64 * K_);
      sa[2*i] = *(const float4*)pa; sa[2*i+1] = *(const float4*)(pa + 4);
      sb[2*i] = *(const float4*)pb; sb[2*i+1] = *(const float4*)(pb + 4);
    }
  };
  auto cvtwrite = [&](int buf) {
    char* A = lds + buf * 65536; char* B = A + 32768;
#pragma unroll
    for (int i = 0; i < 4; ++i) {
      uint4 wa, wb;
      wa.x = cvtpk_(sa[2*i].x, sa[2*i].y);     wa.y = cvtpk_(sa[2*i].z, sa[2*i].w);
      wa.z = cvtpk_(sa[2*i+1].x, sa[2*i+1].y); wa.w = cvtpk_(sa[2*i+1].z, sa[2*i+1].w);
      wb.x = cvtpk_(sb[2*i].x, sb[2*i].y);     wb.y = cvtpk_(sb[2*i].z, sb[2*i].w);
      wb.z = cvtpk_(sb[2*i+1].x, sb[2*i+1].y); wb.w = cvtpk_(sb[2*i+1].z, sb[2*i+1].w);
      *(uint4*)(A + wbyte + i * 8192) = wa;
      *(uint4*)(B + wbyte + i * 8192) = wb;
    }
  };
  auto compute = [&](int buf) {
    const char* A = lds + buf * 65536; const char* B = A + 32768;
#pragma unroll
    for (int kk = 0; kk < 2; ++kk) {
      const int ba = basa0 ^ (kk ? 64 : 0), bb = basb0 ^ (kk ? 64 : 0);
      s16x8 bf[4];
#pragma unroll
      for (int n = 0; n < 4; ++n) bf[n] = *(const s16x8*)(B + bb + n * 2048);
#pragma unroll
      for (int mh = 0; mh < 2; ++mh) {
        s16x8 af[4];
#pragma unroll
        for (int m = 0; m < 4; ++m) af[m] = *(const s16x8*)(A + ba + (mh * 4 + m) * 2048);
        __builtin_amdgcn_s_setprio(1);
#pragma unroll
        for (int m = 0; m < 4; ++m)
#pragma unroll
          for (int n = 0; n < 4; ++n)
            acc[mh*4+m][n] = __builtin_amdgcn_mfma_f32_16x16x32_bf16(af[m], bf[n], acc[mh*4+m][n], 0, 0, 0);
        __builtin_amdgcn_s_setprio(0);
      }
    }
  };
  loadset(0); cvtwrite(0); __syncthreads();
  for (int kt = 0; kt < 16; ++kt) {
    const int cur = kt & 1;
    if (kt + 1 < 16) loadset(kt + 1);
    compute(cur);
    if (kt + 1 < 16) cvtwrite(cur ^ 1);
    __syncthreads();
  }
#pragma unroll
  for (int m = 0; m < 8; ++m) {
    const int row0 = mt * 256 + wr * 128 + m * 16 + ((lane >> 4) << 2);
#pragma unroll
    for (int n = 0; n < 4; ++n) {
      f32x4 a = acc[m][n];
      a.y += a.x; a.z += a.y; a.w += a.z;
      const int col = nt * 256 + wc * 64 + n * 16 + (lane & 15);
      out[(size_t)(row0 + 0) * N_ + col] = a.x;
      out[(size_t)(row0 + 1) * N_ + col] = a.y;
      out[(size_t)(row0 + 2) * N_ + col] = a.z;
      out[(size_t)(row0 + 3) * N_ + col] = a.w;
    }
  }
}

extern "C" void kernel_launch(void* const* d_in, const int* in_sizes, int n_in,
                              void* d_out, int out_size, void* d_ws, size_t ws_size,
                              hipStream_t stream) {
  // setup_inputs order: q, k, v, Wq, Wk, Wv — only v and Wv matter.
  const float* v  = (const float*)d_in[2];
  const float* Wv = (const float*)d_in[5];
  float* out = (float*)d_out;
  (void)in_sizes; (void)n_in; (void)out_size;

  if (ws_size >= WS_NEED) {
    unsigned short* wb = (unsigned short*)d_ws;
    cvt_w<<<dim3(256), dim3(256), 0, stream>>>(Wv, wb);
    hipFuncSetAttribute((const void*)la_gemm11,
                        hipFuncAttributeMaxDynamicSharedMemorySize, 131072);
    la_gemm11<<<dim3(256), dim3(512), 131072, stream>>>(v, wb, out);
  } else {
    hipFuncSetAttribute((const void*)la_gemm_fb,
                        hipFuncAttributeMaxDynamicSharedMemorySize, 131072);
    la_gemm_fb<<<dim3(256), dim3(512), 131072, stream>>>(v, Wv, out);
  }
}